// Round 1
// baseline (166.680 us; speedup 1.0000x reference)
//
#include <hip/hip_runtime.h>

// HierarchicalSoftmax: out[b] = prod_l sigmoid(+/- (W[node]·emb[b] + bias[node]))
// One wave (64 lanes) per sample. D=512 -> 8 floats/lane held in registers.
// Path for leaf v: node labels strictly decrease to 0 (root); padding is all-0,
// so we process entries up to and including the node==0 entry, then stop.
// This avoids needing path_mask (bool dtype) at all.

#define HS_D 512

__global__ __launch_bounds__(256) void hs_kernel(
    const float* __restrict__ emb,     // [B, 512]
    const float* __restrict__ W,       // [V-1, 512]
    const float* __restrict__ bias,    // [V-1]
    const int*   __restrict__ target,  // [B]
    const int*   __restrict__ nodes,   // [V, L]
    const int*   __restrict__ dirs,    // [V, L]
    float*       __restrict__ out,     // [B]
    int B, int L)
{
    const int wid  = blockIdx.x * (blockDim.x >> 6) + (threadIdx.x >> 6);
    const int lane = threadIdx.x & 63;
    if (wid >= B) return;

    // Embedding row resident in registers: lane covers float4 slots {lane, lane+64}
    const float4* e4 = (const float4*)(emb + (size_t)wid * HS_D);
    const float4 e0 = e4[lane];
    const float4 e1 = e4[lane + 64];

    const int t = __builtin_amdgcn_readfirstlane(target[wid]);
    const int* __restrict__ nrow = nodes + (size_t)t * L;
    const int* __restrict__ drow = dirs  + (size_t)t * L;

    float prod = 1.0f;
    for (int l = 0; l < L; ++l) {
        const int node = __builtin_amdgcn_readfirstlane(nrow[l]);
        const int dir  = __builtin_amdgcn_readfirstlane(drow[l]);

        const float4* w4 = (const float4*)(W + (size_t)node * HS_D);
        const float4 w0 = w4[lane];
        const float4 w1 = w4[lane + 64];

        float p = e0.x*w0.x + e0.y*w0.y + e0.z*w0.z + e0.w*w0.w
                + e1.x*w1.x + e1.y*w1.y + e1.z*w1.z + e1.w*w1.w;
        #pragma unroll
        for (int m = 32; m > 0; m >>= 1) p += __shfl_xor(p, m, 64);

        const float s  = p + bias[node];
        const float sg = (dir != 0) ? s : -s;
        prod *= 1.0f / (1.0f + __expf(-sg));

        if (node == 0) break;   // root processed: rest of row is padding (mask=false -> factor 1)
    }

    if (lane == 0) out[wid] = prod;
}

extern "C" void kernel_launch(void* const* d_in, const int* in_sizes, int n_in,
                              void* d_out, int out_size, void* d_ws, size_t ws_size,
                              hipStream_t stream)
{
    const float* emb    = (const float*)d_in[0];
    const float* W      = (const float*)d_in[1];
    const float* bias   = (const float*)d_in[2];
    const int*   target = (const int*)  d_in[3];
    const int*   nodes  = (const int*)  d_in[4];
    const int*   dirs   = (const int*)  d_in[5];
    float*       out    = (float*)d_out;

    const int B = in_sizes[3];              // 4096
    const int V = in_sizes[2] + 1;          // bias has V-1 entries
    const int L = in_sizes[4] / V;          // padded max path length

    const int wavesPerBlock = 4;            // 256 threads
    const int grid = (B + wavesPerBlock - 1) / wavesPerBlock;
    hs_kernel<<<grid, 256, 0, stream>>>(emb, W, bias, target, nodes, dirs, out, B, L);
}

// Round 2
// 162.960 us; speedup vs baseline: 1.0228x; 1.0228x over previous
//
#include <hip/hip_runtime.h>

// HierarchicalSoftmax: out[b] = prod_l sigmoid(+/- (W[node_l]·emb[b] + bias[node_l]))
// One wave per sample; D=512 -> 8 floats/lane in registers.
//
// R1 changes vs R0:
//  - Path metadata (nodes/dirs) preloaded lane-parallel in ONE load; trip count
//    computed up-front via ballot+ffs of "node==0" (root is the last real step,
//    node labels strictly decrease to 0; padding is node==0/mask=false, so the
//    FIRST node==0 position == path length). Removes the data-dependent break
//    that serialized the loop.
//  - Manual 4x unroll: 4 independent W-row loads + 4 interleaved shfl-reduce
//    chains in flight per group -> memory latency parallelism.
//  - readfirstlane'd node indices -> scalar-pipe addressing, scalar bias loads.
//  - fast sigmoid: __expf + v_rcp.

#define HS_D 512

__device__ __forceinline__ float dot8(const float4 e0, const float4 e1,
                                      const float4 a, const float4 b) {
    float p;
    p = e0.x * a.x;
    p = fmaf(e0.y, a.y, p);
    p = fmaf(e0.z, a.z, p);
    p = fmaf(e0.w, a.w, p);
    p = fmaf(e1.x, b.x, p);
    p = fmaf(e1.y, b.y, p);
    p = fmaf(e1.z, b.z, p);
    p = fmaf(e1.w, b.w, p);
    return p;
}

__device__ __forceinline__ float fast_sigmoid(float s) {
    // 1/(1+e^-s); v_rcp_f32 rel err ~1e-6, far under the 2%-of-max threshold
    return __builtin_amdgcn_rcpf(1.0f + __expf(-s));
}

__global__ __launch_bounds__(256) void hs_kernel(
    const float* __restrict__ emb,     // [B, 512]
    const float* __restrict__ W,       // [V-1, 512]
    const float* __restrict__ bias,    // [V-1]
    const int*   __restrict__ target,  // [B]
    const int*   __restrict__ nodes,   // [V, L]
    const int*   __restrict__ dirs,    // [V, L]
    float*       __restrict__ out,     // [B]
    int B, int L)
{
    const int wid  = blockIdx.x * (blockDim.x >> 6) + (threadIdx.x >> 6);
    const int lane = threadIdx.x & 63;
    if (wid >= B) return;

    // Embedding row in registers: lane covers float4 slots {lane, lane+64}
    const float4* e4 = (const float4*)(emb + (size_t)wid * HS_D);
    const float4 e0 = e4[lane];
    const float4 e1 = e4[lane + 64];

    const int t = __builtin_amdgcn_readfirstlane(target[wid]);

    // Lane-parallel preload of the whole path's metadata (L ~ 27 < 64)
    int nval = 0, dval = 0;
    if (lane < L) {
        nval = nodes[(size_t)t * L + lane];
        dval = dirs [(size_t)t * L + lane];
    }
    // First node==0 along the row is the root (= last real step). 1-based pos.
    const unsigned long long rootmask = __ballot(lane < L && nval == 0);
    const int plen = __ffsll((long long)rootmask);
    const unsigned long long dirmask = __ballot(dval != 0);

    float prod = 1.0f;
    int l = 0;

    for (; l + 4 <= plen; l += 4) {
        const int n0 = __builtin_amdgcn_readfirstlane(__shfl(nval, l + 0, 64));
        const int n1 = __builtin_amdgcn_readfirstlane(__shfl(nval, l + 1, 64));
        const int n2 = __builtin_amdgcn_readfirstlane(__shfl(nval, l + 2, 64));
        const int n3 = __builtin_amdgcn_readfirstlane(__shfl(nval, l + 3, 64));

        const float4* w0 = (const float4*)(W + (size_t)n0 * HS_D);
        const float4* w1 = (const float4*)(W + (size_t)n1 * HS_D);
        const float4* w2 = (const float4*)(W + (size_t)n2 * HS_D);
        const float4* w3 = (const float4*)(W + (size_t)n3 * HS_D);

        // 8 independent 16B loads in flight
        const float4 a0 = w0[lane], b0 = w0[lane + 64];
        const float4 a1 = w1[lane], b1 = w1[lane + 64];
        const float4 a2 = w2[lane], b2 = w2[lane + 64];
        const float4 a3 = w3[lane], b3 = w3[lane + 64];

        float p0 = dot8(e0, e1, a0, b0);
        float p1 = dot8(e0, e1, a1, b1);
        float p2 = dot8(e0, e1, a2, b2);
        float p3 = dot8(e0, e1, a3, b3);

        // 4 interleaved reduce chains hide the cross-lane-op latency
        #pragma unroll
        for (int m = 32; m > 0; m >>= 1) {
            p0 += __shfl_xor(p0, m, 64);
            p1 += __shfl_xor(p1, m, 64);
            p2 += __shfl_xor(p2, m, 64);
            p3 += __shfl_xor(p3, m, 64);
        }

        float s0 = p0 + bias[n0];
        float s1 = p1 + bias[n1];
        float s2 = p2 + bias[n2];
        float s3 = p3 + bias[n3];
        s0 = ((dirmask >> (l + 0)) & 1ull) ? s0 : -s0;
        s1 = ((dirmask >> (l + 1)) & 1ull) ? s1 : -s1;
        s2 = ((dirmask >> (l + 2)) & 1ull) ? s2 : -s2;
        s3 = ((dirmask >> (l + 3)) & 1ull) ? s3 : -s3;

        prod *= fast_sigmoid(s0) * fast_sigmoid(s1)
              * fast_sigmoid(s2) * fast_sigmoid(s3);
    }

    for (; l < plen; ++l) {
        const int n = __builtin_amdgcn_readfirstlane(__shfl(nval, l, 64));
        const float4* w = (const float4*)(W + (size_t)n * HS_D);
        const float4 a = w[lane], b = w[lane + 64];
        float p = dot8(e0, e1, a, b);
        #pragma unroll
        for (int m = 32; m > 0; m >>= 1) p += __shfl_xor(p, m, 64);
        float s = p + bias[n];
        s = ((dirmask >> l) & 1ull) ? s : -s;
        prod *= fast_sigmoid(s);
    }

    if (lane == 0) out[wid] = prod;
}

extern "C" void kernel_launch(void* const* d_in, const int* in_sizes, int n_in,
                              void* d_out, int out_size, void* d_ws, size_t ws_size,
                              hipStream_t stream)
{
    const float* emb    = (const float*)d_in[0];
    const float* W      = (const float*)d_in[1];
    const float* bias   = (const float*)d_in[2];
    const int*   target = (const int*)  d_in[3];
    const int*   nodes  = (const int*)  d_in[4];
    const int*   dirs   = (const int*)  d_in[5];
    float*       out    = (float*)d_out;

    const int B = in_sizes[3];              // 4096
    const int V = in_sizes[2] + 1;          // bias has V-1 entries
    const int L = in_sizes[4] / V;          // padded max path length (~27)

    const int wavesPerBlock = 4;            // 256 threads
    const int grid = (B + wavesPerBlock - 1) / wavesPerBlock;
    hs_kernel<<<grid, 256, 0, stream>>>(emb, W, bias, target, nodes, dirs, out, B, L);
}